// Round 7
// baseline (297.712 us; speedup 1.0000x reference)
//
#include <hip/hip_runtime.h>
#include <math.h>

#define C_      22      // NUM_CLASSES
#define SKIP_   20
#define NSTEP_  200
#define STEP_   4.0f
#define INL_T_  0.9f
#define LAB_T_  500
#define B_      2
#define H_      480
#define W_      640
#define HW_     (H_ * W_)       // 307200
#define P_      (HW_ / SKIP_)   // 15360
#define NPTS_   (B_ * P_)       // 30720

#define TS_       64            // spatial tile side
#define TILES_X_  (W_ / TS_)    // 10
#define NTILES_Y_ 8             // covers y 0..511 (exact check restricts to 479)
#define NTILES_   (TILES_X_ * NTILES_Y_)   // 80
#define NPLANES_  (B_ * (C_ - 1))          // 42 live planes (c=0 dead)
#define NPT_      (NPLANES_ * NTILES_)     // 3360 plane-tiles

#define K1_BLOCKS_   (NPTS_ / 256)         // 120: compaction + hist blocks
#define SLAB_        (B_ * HW_ / K1_BLOCKS_) // 5120 px histogram slab per block
#define HB_PER_IMG_  (K1_BLOCKS_ / B_)     // 60 partial-hist rows per image

#define KEY_INIT_ 0x00000000FFFFFFFFull    // (count 0, idx 0) under the key encoding

// ============================================================================
// Kernel 1 (120 blocks): deterministic per-block point compaction (LDS-staged,
// coalesced segment write + fully-written directory -> NO zeroed counters
// needed) + per-block label-histogram partials (plain stores) + block-0 inits
// of key/pdone/out-c0 (consumed only by k2 -> stream-ordered).
// Record: {x|y<<16, z, dnx, dny}.
// ============================================================================
__global__ __launch_bounds__(256) void compact_hist_kernel(const int* __restrict__ label,
                                                           const float* __restrict__ vp,
                                                           uint4* __restrict__ cls,
                                                           unsigned int* __restrict__ dir,
                                                           unsigned int* __restrict__ partials,
                                                           unsigned int* __restrict__ pdone,
                                                           unsigned long long* __restrict__ key,
                                                           float* __restrict__ out) {
    __shared__ int   hcnt[NPLANES_];
    __shared__ int   hstart[NPLANES_];
    __shared__ uint4 stage[256];
    __shared__ int   hh[C_];
    const int tid = threadIdx.x;
    const int bk  = blockIdx.x;

    if (bk == 0) {   // init state consumed only by k2 (kernel-boundary ordered)
        if (tid < B_ * C_) key[tid] = KEY_INIT_;
        if (tid >= 64 && tid < 64 + NPLANES_) pdone[tid - 64] = 0u;
        if (tid >= 128 && tid < 128 + 14) out[tid - 128] = 0.0f;            // row (0, c=0)
        if (tid >= 160 && tid < 160 + 14) out[C_ * 14 + (tid - 160)] = 0.0f; // row (1, c=0)
    }

    // ---- phase A: compaction of this block's 256 sample points ----
    for (int i = tid; i < NPLANES_; i += 256) hcnt[i] = 0;
    __syncthreads();
    int g   = bk * 256 + tid;            // 0..NPTS_-1 (exact)
    int b   = g / P_;
    int pi  = g - b * P_;
    int idx = pi * SKIP_;
    int lab = label[b * HW_ + idx];
    int p = -1, myrank = 0;
    uint4 r;
    if (lab > 0) {
        int xi = idx % W_, yi = idx / W_;
        const float* s = vp + ((size_t)(b * HW_ + idx) * (C_ * 3)) + lab * 3;
        float dx = s[0], dy = s[1], z = s[2];
        float nrm = sqrtf(__fadd_rn(__fmul_rn(dx, dx), __fmul_rn(dy, dy))) + 1e-9f;
        float dnx = dx / nrm, dny = dy / nrm;
        p = b * (C_ - 1) + (lab - 1);
        r.x = (unsigned)xi | ((unsigned)yi << 16);
        r.y = __float_as_uint(z);
        r.z = __float_as_uint(dnx);
        r.w = __float_as_uint(dny);
        myrank = atomicAdd(&hcnt[p], 1);
    }
    __syncthreads();
    if (tid < 64) {   // wave-0 inclusive shfl-scan over 42 plane counts
        int v = (tid < NPLANES_) ? hcnt[tid] : 0;
        int orig = v;
        #pragma unroll
        for (int s = 1; s < 64; s <<= 1) {
            int u = __shfl_up(v, s);
            if (tid >= s) v += u;
        }
        if (tid < NPLANES_) hstart[tid] = v - orig;   // exclusive start
    }
    __syncthreads();
    if (p >= 0) stage[hstart[p] + myrank] = r;
    __syncthreads();
    cls[bk * 256 + tid] = stage[tid];    // tail beyond fg-count never read (dir-bounded)
    if (tid < NPLANES_)
        dir[bk * NPLANES_ + tid] = ((unsigned)hstart[tid] << 16) | (unsigned)hcnt[tid];

    // ---- phase B: label-histogram partials over a 5120-px slab ----
    if (tid < C_) hh[tid] = 0;
    __syncthreads();
    const int base = bk * SLAB_;
    #pragma unroll
    for (int rnd = 0; rnd < SLAB_ / 1024; ++rnd) {   // 5 int4 rounds
        int4 l4 = *(const int4*)(label + base + rnd * 1024 + tid * 4);
        atomicAdd(&hh[l4.x], 1);
        atomicAdd(&hh[l4.y], 1);
        atomicAdd(&hh[l4.z], 1);
        atomicAdd(&hh[l4.w], 1);
    }
    __syncthreads();
    if (tid < C_) partials[bk * C_ + tid] = (unsigned)hh[tid];
}

// ============================================================================
// Kernel 2 (3360 blocks): analytic ray->tile rasterize + argmax per plane-tile;
// per-plane LAST-ARRIVER (done-counter, no waiting) re-gathers the plane's
// records, computes inlier sums + class pixel count, finalizes its output row.
// key = (count << 32) | (0xFFFFFFFF - idx): max key == max count, tie -> min idx.
// ============================================================================
__global__ __launch_bounds__(256) void raster_argmax_finalize_kernel(
        const uint4* __restrict__ cls, const unsigned int* __restrict__ dir,
        unsigned long long* __restrict__ key, unsigned int* __restrict__ pdone,
        const unsigned int* __restrict__ partials,
        const float* __restrict__ extents, const float* __restrict__ meta,
        float* __restrict__ out) {
    __shared__ unsigned int tile[TS_ * TS_ / 2];   // u16-packed, 8 KB
    __shared__ int ebase[128];                     // segment exclusive bases
    __shared__ int scnt[128];
    __shared__ int gst[128];                       // segment global record start
    __shared__ unsigned int sv[4];
    __shared__ int          si[4];
    __shared__ float zp[4];
    __shared__ float np[4];
    __shared__ int last_flag;
    __shared__ int Msh;
    __shared__ unsigned long long kbro;
    const int tid = threadIdx.x;
    int pt = blockIdx.x;                 // 0..3359
    int p  = pt / NTILES_;
    int tl = pt % NTILES_;
    int b = p / (C_ - 1);
    int c = p % (C_ - 1) + 1;
    int x0 = (tl % TILES_X_) * TS_;
    int y0 = (tl / TILES_X_) * TS_;

    {   // zero tile with uint4 stores (2 per thread)
        uint4* t4 = (uint4*)tile;
        t4[tid]       = make_uint4(0u, 0u, 0u, 0u);
        t4[tid + 256] = make_uint4(0u, 0u, 0u, 0u);
    }
    // ---- segment directory load + prefix-sum (Hillis-Steele over 128) ----
    if (tid < 128) {
        int cnt = 0, st = 0;
        if (tid < K1_BLOCKS_) {
            unsigned w = dir[tid * NPLANES_ + p];
            cnt = (int)(w & 0xFFFFu);
            st  = tid * 256 + (int)(w >> 16);
        }
        scnt[tid] = cnt; gst[tid] = st; ebase[tid] = cnt;
    }
    __syncthreads();
    for (int s = 1; s < 128; s <<= 1) {
        int v = 0;
        if (tid < 128) { v = ebase[tid]; if (tid >= s) v += ebase[tid - s]; }
        __syncthreads();
        if (tid < 128) ebase[tid] = v;
        __syncthreads();
    }
    if (tid == 0) Msh = ebase[127];      // total records of this plane
    __syncthreads();
    if (tid < 128) ebase[tid] -= scnt[tid];   // inclusive -> exclusive
    __syncthreads();
    const int M = Msh;

    // ---- rasterize: conservative ray∩tile interval -> exact per-step votes ----
    const float lox = (float)x0 - 0.51f, hix = (float)x0 + 63.51f;
    const float loy = (float)y0 - 0.51f, hiy = (float)y0 + 63.51f;
    for (int rI = tid; rI < M; rI += 256) {
        int lo = 0, hi = K1_BLOCKS_ - 1;          // binary search segment
        while (lo < hi) { int mid = (lo + hi + 1) >> 1; if (ebase[mid] <= rI) lo = mid; else hi = mid - 1; }
        uint4 rec = cls[gst[lo] + (rI - ebase[lo])];
        float xs  = (float)(rec.x & 0xFFFFu);
        float ys  = (float)(rec.x >> 16);
        float dnx = __uint_as_float(rec.z);
        float dny = __uint_as_float(rec.w);
        float tLo = STEP_, tHi = (float)NSTEP_ * STEP_;
        bool empty = false;
        if (fabsf(dnx) > 1e-8f) {
            float ta = (lox - xs) / dnx, tb = (hix - xs) / dnx;
            float t1 = fminf(ta, tb), t2 = fmaxf(ta, tb);
            tLo = fmaxf(tLo, t1); tHi = fminf(tHi, t2);
        } else if (xs < lox || xs > hix) { empty = true; }
        if (fabsf(dny) > 1e-8f) {
            float ta = (loy - ys) / dny, tb = (hiy - ys) / dny;
            float t1 = fminf(ta, tb), t2 = fmaxf(ta, tb);
            tLo = fmaxf(tLo, t1); tHi = fminf(tHi, t2);
        } else if (ys < loy || ys > hiy) { empty = true; }
        if (empty || tLo > tHi) continue;
        int iB = (int)floorf(tLo * 0.25f) - 2; if (iB < 0) iB = 0;
        int iE = (int)ceilf(tHi * 0.25f) + 2;  if (iE > NSTEP_ - 1) iE = NSTEP_ - 1;
        for (int i = iB; i <= iE; ++i) {
            float t = (float)(i + 1) * STEP_;
            float cx = __fadd_rn(xs, __fmul_rn(dnx, t));   // bit-identical to reference path
            float cy = __fadd_rn(ys, __fmul_rn(dny, t));
            float cxr = rintf(cx);                          // round-half-even == jnp.round
            float cyr = rintf(cy);
            if (cxr >= 0.0f && cxr <= (float)(W_ - 1) && cyr >= 0.0f && cyr <= (float)(H_ - 1)) {
                int lx = (int)cxr - x0;
                int ly = (int)cyr - y0;
                if ((unsigned)lx < TS_ && (unsigned)ly < TS_) {
                    int cell = ly * TS_ + lx;
                    atomicAdd(&tile[cell >> 1], 1u << ((cell & 1) * 16));
                }
            }
        }
    }
    __syncthreads();
    // ---- argmax: conflict-free strided scan + 64-lane shuffle reduce ----
    unsigned bv = 0u; int bi = 0;
    {
        unsigned w0 = tile[tid];
        bv = w0 & 0xFFFFu; bi = tid * 2;
        unsigned hi2 = w0 >> 16;
        if (hi2 > bv) { bv = hi2; bi = tid * 2 + 1; }
    }
    #pragma unroll
    for (int j = 1; j < 8; ++j) {
        int ix = tid + j * 256;
        unsigned w = tile[ix];
        unsigned lo2 = w & 0xFFFFu, hi2 = w >> 16;
        if (lo2 > bv) { bv = lo2; bi = ix * 2; }
        if (hi2 > bv) { bv = hi2; bi = ix * 2 + 1; }
    }
    #pragma unroll
    for (int s = 1; s < 64; s <<= 1) {
        unsigned ov = (unsigned)__shfl_xor((int)bv, s);
        int      oi = __shfl_xor(bi, s);
        if (ov > bv || (ov == bv && oi < bi)) { bv = ov; bi = oi; }
    }
    if ((tid & 63) == 0) { sv[tid >> 6] = bv; si[tid >> 6] = bi; }
    __syncthreads();
    if (tid == 0) {
        unsigned fbv = sv[0]; int fbi = si[0];
        #pragma unroll
        for (int w = 1; w < 4; ++w) {
            unsigned ov = sv[w]; int oi = si[w];
            if (ov > fbv || (ov == fbv && oi < fbi)) { fbv = ov; fbi = oi; }
        }
        if (fbv > 0u) {   // zero-vote tile can never beat KEY_INIT (count0,idx0)
            int ly = fbi >> 6, lx = fbi & 63;
            unsigned gidx = (unsigned)((y0 + ly) * W_ + (x0 + lx));
            unsigned long long k = ((unsigned long long)fbv << 32)
                                 | (unsigned long long)(0xFFFFFFFFu - gidx);
            atomicMax(&key[b * C_ + c], k);
        }
    }

    // ---- per-plane completion: last-arriver (no waiting) inlier + finalize ----
    if (tid == 0) {
        __threadfence();                 // release our atomicMax(key)
        unsigned prev = atomicAdd(&pdone[p], 1u);
        last_flag = (prev == (unsigned)(NTILES_ - 1)) ? 1 : 0;
    }
    __syncthreads();
    if (!last_flag) return;
    __threadfence();                     // acquire all 80 blocks' key contributions
    if (tid == 0) kbro = atomicAdd(&key[b * C_ + c], 0ull);   // device-scope read
    __syncthreads();
    unsigned long long k = kbro;
    int pkv = (int)(0xFFFFFFFFu - (unsigned int)(k & 0xFFFFFFFFull));
    float pkx = (float)(pkv % W_), pky = (float)(pkv / W_);

    float zacc = 0.0f, nacc = 0.0f;
    for (int rI = tid; rI < M; rI += 256) {
        int lo = 0, hi = K1_BLOCKS_ - 1;
        while (lo < hi) { int mid = (lo + hi + 1) >> 1; if (ebase[mid] <= rI) lo = mid; else hi = mid - 1; }
        uint4 rec = cls[gst[lo] + (rI - ebase[lo])];
        float xs  = (float)(rec.x & 0xFFFFu);
        float ys  = (float)(rec.x >> 16);
        float z   = __uint_as_float(rec.y);
        float dnx = __uint_as_float(rec.z);
        float dny = __uint_as_float(rec.w);
        float dvx = __fsub_rn(pkx, xs), dvy = __fsub_rn(pky, ys);
        float nrm2 = sqrtf(__fadd_rn(__fmul_rn(dvx, dvx), __fmul_rn(dvy, dvy))) + 1e-9f;
        dvx /= nrm2; dvy /= nrm2;
        float dot = __fadd_rn(__fmul_rn(dnx, dvx), __fmul_rn(dny, dvy));
        if (dot > INL_T_) { zacc += z; nacc += 1.0f; }
    }
    #pragma unroll
    for (int s = 1; s < 64; s <<= 1) {
        zacc += __shfl_xor(zacc, s);
        nacc += __shfl_xor(nacc, s);
    }
    if ((tid & 63) == 0) { zp[tid >> 6] = zacc; np[tid >> 6] = nacc; }
    __syncthreads();
    if (tid >= 64) return;
    // wave 0: sum this class's histogram partials (60 rows) + finalize
    int cs = (tid < HB_PER_IMG_) ? (int)partials[(b * HB_PER_IMG_ + tid) * C_ + c] : 0;
    #pragma unroll
    for (int s = 1; s < 64; s <<= 1) cs += __shfl_xor(cs, s);
    if (tid != 0) return;
    float zsum_t = zp[0] + zp[1] + zp[2] + zp[3];
    float ninl_t = np[0] + np[1] + np[2] + np[3];
    float* o = out + (b * C_ + c) * 14;
    if (cs < LAB_T_) {                   // c > 0 always here
        #pragma unroll
        for (int k2 = 0; k2 < 14; ++k2) o[k2] = 0.0f;
        return;
    }
    float depth = zsum_t / fmaxf(ninl_t, 1.0f);
    float z_safe = (fabsf(depth) > 0.001f) ? depth : 1.0f;
    float fx = meta[b * 48 + 0];
    float fy = meta[b * 48 + 4];
    const float* e = extents + c * 3;
    float diam = sqrtf(e[0]*e[0] + e[1]*e[1] + e[2]*e[2]);
    float vmax = (float)(unsigned int)(k >> 32);
    float half_w = ((0.5f * diam) * fx) / z_safe;
    float half_h = ((0.5f * diam) * fy) / z_safe;
    o[0] = (float)b;
    o[1] = (float)c;
    o[2] = pkx - half_w;
    o[3] = pky - half_h;
    o[4] = pkx + half_w;
    o[5] = pky + half_h;
    o[6] = vmax;
    const float* Ki = meta + b * 48 + 9;   // Kinv row-major 3x3
    float rx = Ki[0]*pkx + Ki[1]*pky + Ki[2];
    float ry = Ki[3]*pkx + Ki[4]*pky + Ki[5];
    float rz = Ki[6]*pkx + Ki[7]*pky + Ki[8];
    o[7]  = 1.0f;
    o[8]  = 0.0f;
    o[9]  = 0.0f;
    o[10] = 0.0f;
    o[11] = depth * rx;
    o[12] = depth * ry;
    o[13] = depth * rz;
}

extern "C" void kernel_launch(void* const* d_in, const int* in_sizes, int n_in,
                              void* d_out, int out_size, void* d_ws, size_t ws_size,
                              hipStream_t stream) {
    const int*   label   = (const int*)d_in[0];    // (B,H,W) int32
    const float* vp      = (const float*)d_in[1];  // (B,H,W,66) f32
    const float* extents = (const float*)d_in[2];  // (22,3) f32
    const float* meta    = (const float*)d_in[4];  // (B,48) f32
    float* out = (float*)d_out;                    // (B,C,14) = 616 f32

    char* ws = (char*)d_ws;
    size_t off = 0;
    uint4* cls = (uint4*)(ws + off);                 // 30720*16 = 491520 B (dir-bounded reads)
    off += (size_t)NPTS_ * sizeof(uint4);
    unsigned int* dir      = (unsigned int*)(ws + off); off += K1_BLOCKS_ * NPLANES_ * sizeof(unsigned int); // 20160 B, fully written
    unsigned int* partials = (unsigned int*)(ws + off); off += K1_BLOCKS_ * C_ * sizeof(unsigned int);       // 10560 B, fully written
    unsigned int* pdone    = (unsigned int*)(ws + off); off += NPLANES_ * sizeof(unsigned int);              // zeroed by k1 blk0
    off = (off + 7) & ~(size_t)7;
    unsigned long long* key = (unsigned long long*)(ws + off);   // init'd by k1 blk0
    off += B_ * C_ * sizeof(unsigned long long);

    // no memset: every workspace word is either fully written by k1 before k2
    // reads it, bounded by dir counts, or initialized by k1 block 0.

    compact_hist_kernel<<<K1_BLOCKS_, 256, 0, stream>>>(
        label, vp, cls, dir, partials, pdone, key, out);
    raster_argmax_finalize_kernel<<<NPT_, 256, 0, stream>>>(
        cls, dir, key, pdone, partials, extents, meta, out);
}